// Round 10
// baseline (370.313 us; speedup 1.0000x reference)
//
#include <hip/hip_runtime.h>
#include <stdint.h>
#include <stddef.h>

// Problem constants
#define B_    16
#define N_SEQ 4096
#define C_    512
#define H_    8
#define E_    64
#define M_TOT (B_ * N_SEQ)   // 65536
#define QKVN  (3 * C_)       // 1536

typedef __attribute__((ext_vector_type(8))) short short8;
typedef __attribute__((ext_vector_type(4))) short s16x4;
typedef __attribute__((ext_vector_type(4))) float f32x4;

__device__ __forceinline__ unsigned short f2bf(float f) {
  uint32_t u = __builtin_bit_cast(uint32_t, f);
  return (unsigned short)((u + 0x7fffu + ((u >> 16) & 1u)) >> 16);  // RNE
}
__device__ __forceinline__ float bf2f(unsigned short h) {
  uint32_t u = ((uint32_t)h) << 16;
  return __builtin_bit_cast(float, u);
}

// ---------------------------------------------------------------- convert
__global__ __launch_bounds__(256) void cvt_bf16(const float* __restrict__ in,
                                                unsigned short* __restrict__ out) {
  size_t i = ((size_t)blockIdx.x * 256 + threadIdx.x) * 8;
  float4 a = *(const float4*)(in + i);
  float4 b = *(const float4*)(in + i + 4);
  short8 o;
  o[0] = (short)f2bf(a.x); o[1] = (short)f2bf(a.y);
  o[2] = (short)f2bf(a.z); o[3] = (short)f2bf(a.w);
  o[4] = (short)f2bf(b.x); o[5] = (short)f2bf(b.y);
  o[6] = (short)f2bf(b.z); o[7] = (short)f2bf(b.w);
  *(short8*)(out + i) = o;
}

#define GLD16(g, l)                                                              \
  __builtin_amdgcn_global_load_lds(                                              \
      (const __attribute__((address_space(1))) void*)(g),                        \
      (__attribute__((address_space(3))) void*)(l), 16, 0, 0)

// ---------------------------------------------------------------- GEMM (C = A * B^T), bf16 in, f32 accum
// Occupancy-first design: block 128x256, 4 waves (wave-tile 128x64), BK=32,
// double-buffered LDS = 48 KiB -> 2 blocks/CU (LDS 96 KiB, ~230 regs/wave =
// 2 waves/SIMD). One block's K-loop overlaps the other's epilogue/prologue.
// Paired-row XOR swizzle (BK=32: row = 64B = 4 slots; pair = 128B = 8 slots):
//   LDS 16B-slot index within pair p: c' = ((r&1)*4 + kslot) ^ (p&7), p = r>>1.
//   - read (r, kslot=fg): every 8-lane service group covers all 8 bank-quads
//     (hand-verified bijection) -> conflict-free ds_read_b128.
//   - staging: LDS position q (16B units) holds global (p=q>>3, c=(q&7)^(p&7))
//     -> srcRow = 2p + (c>>2), srcSlot = c&3. 8 threads cover 2 full 64B lines
//     (lane-permuted) -> coalescing preserved; LDS dest stays linear (tid*16).
// Schedule per K-tile (R8-proven): STAGE(t+1) -> swizzled ds_read(t) ->
//   setprio(1) 32 MFMA setprio(0) -> __syncthreads() (drains vmcnt).
// MODE 1: qkv epilogue -> bf16 store, relu+0.125 on cols < 1024; ksum for k cols
// MODE 2: f32 store + bias
template <int MODE>
__global__ __launch_bounds__(256, 2) void gemm_bt(
    const unsigned short* __restrict__ A, const unsigned short* __restrict__ Bm,
    void* __restrict__ Cout, const float* __restrict__ bias,
    float* __restrict__ ksum, int M, int N, int NT) {
  const int K = 512;
  __shared__ unsigned short As[2][128 * 32];   // 16 KiB
  __shared__ unsigned short Bs[2][256 * 32];   // 32 KiB
  // XCD-aware bijective swizzle (grid % 8 == 0)
  const int q8 = gridDim.x >> 3;
  int bid = blockIdx.x;
  bid = (bid & 7) * q8 + (bid >> 3);
  const int mt = bid / NT, nt = bid - mt * NT;
  const int row0 = mt << 7, col0 = nt << 8;
  const int tid = threadIdx.x;
  const int lane = tid & 63, wave = tid >> 6;   // wave = wn (0..3)
  const int fr = lane & 15, fg = lane >> 4;

  // staging source pointers (inverse paired swizzle)
  const unsigned short* sA[2];
  const unsigned short* sB[4];
#pragma unroll
  for (int i = 0; i < 2; i++) {
    const int q = i * 256 + tid, p = q >> 3, c = (q & 7) ^ (p & 7);
    sA[i] = A + (size_t)(row0 + 2 * p + (c >> 2)) * K + (c & 3) * 8;
  }
#pragma unroll
  for (int i = 0; i < 4; i++) {
    const int q = i * 256 + tid, p = q >> 3, c = (q & 7) ^ (p & 7);
    sB[i] = Bm + (size_t)(col0 + 2 * p + (c >> 2)) * K + (c & 3) * 8;
  }

  f32x4 acc[8][4] = {};

#define STAGE(kt)                                                  \
  {                                                                \
    unsigned short* dA = &As[(kt) & 1][tid * 8];                   \
    unsigned short* dB = &Bs[(kt) & 1][tid * 8];                   \
    GLD16(sA[0] + (kt) * 32, dA);                                  \
    GLD16(sA[1] + (kt) * 32, dA + 2048);                           \
    GLD16(sB[0] + (kt) * 32, dB);                                  \
    GLD16(sB[1] + (kt) * 32, dB + 2048);                           \
    GLD16(sB[2] + (kt) * 32, dB + 4096);                           \
    GLD16(sB[3] + (kt) * 32, dB + 6144);                           \
  }

  STAGE(0);
  __syncthreads();   // drain: tile 0 resident

  for (int kt = 0; kt < 16; ++kt) {
    if (kt < 15) STAGE(kt + 1);
    const unsigned short* bufA = As[kt & 1];
    const unsigned short* bufB = Bs[kt & 1];
    short8 af[8], bg[4];
#pragma unroll
    for (int m = 0; m < 8; m++) {
      const int r = m * 16 + fr, p = r >> 1;
      const int cp = (((r & 1) << 2) | fg) ^ (p & 7);
      af[m] = *(const short8*)&bufA[p * 64 + cp * 8];
    }
#pragma unroll
    for (int n = 0; n < 4; n++) {
      const int r = wave * 64 + n * 16 + fr, p = r >> 1;
      const int cp = (((r & 1) << 2) | fg) ^ (p & 7);
      bg[n] = *(const short8*)&bufB[p * 64 + cp * 8];
    }
    __builtin_amdgcn_s_setprio(1);
#pragma unroll
    for (int m = 0; m < 8; m++)
#pragma unroll
      for (int n = 0; n < 4; n++)
        acc[m][n] = __builtin_amdgcn_mfma_f32_16x16x32_bf16(af[m], bg[n], acc[m][n], 0, 0, 0);
    __builtin_amdgcn_s_setprio(0);
    __syncthreads();   // separates next STAGE's writes from this tile's readers; drains vmcnt
  }
#undef STAGE

  if (MODE == 1) {
    unsigned short* Cq = (unsigned short*)Cout;
    const int cw0 = col0 + wave * 64;
    const bool isqk = (cw0 < 2 * C_);
    const bool isk = (cw0 >= C_) && (cw0 < 2 * C_);
    float ksp[4] = {0.f, 0.f, 0.f, 0.f};
#pragma unroll
    for (int m = 0; m < 8; m++) {
      const int r0 = row0 + m * 16 + fg * 4;
#pragma unroll
      for (int n = 0; n < 4; n++) {
        const int c = cw0 + n * 16 + fr;
#pragma unroll
        for (int r = 0; r < 4; r++) {
          float v = acc[m][n][r];
          if (isqk) v = fmaxf(v, 0.0f) + 0.125f;   // relu + E^-0.5
          if (isk) ksp[n] += v;
          Cq[(size_t)(r0 + r) * N + c] = f2bf(v);
        }
      }
    }
    if (isk) {
      const int b = row0 >> 12;
#pragma unroll
      for (int n = 0; n < 4; n++) {
        float s = ksp[n];
        s += __shfl_xor(s, 16, 64);
        s += __shfl_xor(s, 32, 64);
        if (lane < 16) {
          const int cc = cw0 + n * 16 + lane - C_;  // 0..511
          atomicAdd(&ksum[(size_t)((b << 3) + (cc >> 6)) * 64 + (cc & 63)], s);
        }
      }
    }
  } else {
    float* Cf = (float*)Cout;
#pragma unroll
    for (int m = 0; m < 8; m++) {
      const int r0 = row0 + m * 16 + fg * 4;
#pragma unroll
      for (int n = 0; n < 4; n++) {
        const int c = col0 + wave * 64 + n * 16 + fr;
        const float bb = bias[c];
#pragma unroll
        for (int r = 0; r < 4; r++)
          Cf[(size_t)(r0 + r) * N + c] = acc[m][n][r] + bb;
      }
    }
  }
}

// ---------------------------------------------------------------- KV^T via MFMA
// KVT[bh][f][e] += sum_{n in chunk} v[n][f] * k_[n][e]
// grid: 128 bh * 8 chunks; block 256 (4 waves); wave w owns f-rows [16w,16w+16)
__global__ __launch_bounds__(256) void kv_mfma(const unsigned short* __restrict__ qkv,
                                               float* __restrict__ KVT) {
  const int bid = blockIdx.x;
  const int ch = bid & 7, bh = bid >> 3;
  const int h = bh & 7, b = bh >> 3;
  const int n0 = ch << 9;  // 512-row chunk
  __shared__ unsigned short ktile[64][68];
  __shared__ unsigned short vtile[64][68];
  const int tid = threadIdx.x;
  const int lane = tid & 63, w = tid >> 6;
  const int fr = lane & 15, fg = lane >> 4;
  const int srow = tid >> 3;            // 0..31
  const int sseg = (tid & 7) << 3;      // 0..56 step 8
  const unsigned short* gk = qkv + (size_t)(b * N_SEQ + n0 + srow) * QKVN + C_ + h * E_ + sseg;
  const unsigned short* gv = gk + C_;   // v is +512 elems within the row

  f32x4 acc[4] = {};
  short8 pk0, pk1, pv0, pv1;
  pk0 = *(const short8*)gk;
  pk1 = *(const short8*)(gk + (size_t)32 * QKVN);
  pv0 = *(const short8*)gv;
  pv1 = *(const short8*)(gv + (size_t)32 * QKVN);

  for (int it = 0; it < 8; ++it) {
    {
      s16x4* dk0 = (s16x4*)&ktile[srow][sseg];
      s16x4* dk1 = (s16x4*)&ktile[srow + 32][sseg];
      s16x4* dv0 = (s16x4*)&vtile[srow][sseg];
      s16x4* dv1 = (s16x4*)&vtile[srow + 32][sseg];
      const s16x4* s;
      s = (const s16x4*)&pk0; dk0[0] = s[0]; dk0[1] = s[1];
      s = (const s16x4*)&pk1; dk1[0] = s[0]; dk1[1] = s[1];
      s = (const s16x4*)&pv0; dv0[0] = s[0]; dv0[1] = s[1];
      s = (const s16x4*)&pv1; dv1[0] = s[0]; dv1[1] = s[1];
    }
    __syncthreads();
    if (it < 7) {
      const unsigned short* nk = gk + (size_t)(it + 1) * 64 * QKVN;
      const unsigned short* nv = gv + (size_t)(it + 1) * 64 * QKVN;
      pk0 = *(const short8*)nk;
      pk1 = *(const short8*)(nk + (size_t)32 * QKVN);
      pv0 = *(const short8*)nv;
      pv1 = *(const short8*)(nv + (size_t)32 * QKVN);
    }
#pragma unroll
    for (int ks = 0; ks < 2; ++ks) {
      const int kb = ks * 32;
      short8 av, bk0, bk1, bk2, bk3;
#pragma unroll
      for (int j = 0; j < 8; ++j) {
        const int row = kb + fg * 8 + j;
        av[j]  = (short)vtile[row][w * 16 + fr];
        bk0[j] = (short)ktile[row][fr];
        bk1[j] = (short)ktile[row][16 + fr];
        bk2[j] = (short)ktile[row][32 + fr];
        bk3[j] = (short)ktile[row][48 + fr];
      }
      acc[0] = __builtin_amdgcn_mfma_f32_16x16x32_bf16(av, bk0, acc[0], 0, 0, 0);
      acc[1] = __builtin_amdgcn_mfma_f32_16x16x32_bf16(av, bk1, acc[1], 0, 0, 0);
      acc[2] = __builtin_amdgcn_mfma_f32_16x16x32_bf16(av, bk2, acc[2], 0, 0, 0);
      acc[3] = __builtin_amdgcn_mfma_f32_16x16x32_bf16(av, bk3, acc[3], 0, 0, 0);
    }
    __syncthreads();
  }

  const size_t fbase = (size_t)bh * 64 + w * 16 + fg * 4;
#pragma unroll
  for (int e = 0; e < 4; ++e)
#pragma unroll
    for (int r = 0; r < 4; ++r)
      atomicAdd(&KVT[(fbase + r) * 64 + e * 16 + fr], acc[e][r]);
}

// ---------------------------------------------------------------- attention output
__global__ __launch_bounds__(256) void attn_out(const unsigned short* __restrict__ qkv,
                                                const float* __restrict__ KVT,
                                                const float* __restrict__ ksum,
                                                unsigned short* __restrict__ hout) {
  const int bid = blockIdx.x;
  const int nc = bid & 63, bh = bid >> 6;
  const int h = bh & 7, b = bh >> 3;
  const int n0 = nc << 6;  // 64-row chunk
  __shared__ float qs[64][68];
  __shared__ float denp[64][4];
  __shared__ float zl[64];
  __shared__ float kss[64];
  const int t = threadIdx.x;

#pragma unroll
  for (int half = 0; half < 2; half++) {
    const int row = (t >> 3) + half * 32;
    const int e0 = (t & 7) * 8;
    const unsigned short* srcq = qkv + (size_t)(b * N_SEQ + n0 + row) * QKVN + h * E_ + e0;
    short8 raw = *(const short8*)srcq;
#pragma unroll
    for (int i = 0; i < 8; i++) qs[row][e0 + i] = bf2f((unsigned short)raw[i]);
  }
  if (t < 64) kss[t] = ksum[bh * 64 + t];
  __syncthreads();

  {
    const int r = t >> 2, qp = t & 3;
    float s = 0.f;
#pragma unroll
    for (int e = 0; e < 16; e++) s = fmaf(qs[r][qp * 16 + e], kss[qp * 16 + e], s);
    denp[r][qp] = s;
  }
  __syncthreads();
  if (t < 64) zl[t] = 1.0f / (denp[t][0] + denp[t][1] + denp[t][2] + denp[t][3] + 1e-6f);
  __syncthreads();

  const int f = t & 63, rg = t >> 6;
  float kvc[64];
  const float* kvp = KVT + (size_t)bh * 4096 + (size_t)f * 64;
#pragma unroll
  for (int i = 0; i < 16; i++) {
    float4 v4 = *(const float4*)(kvp + i * 4);
    kvc[4 * i] = v4.x; kvc[4 * i + 1] = v4.y; kvc[4 * i + 2] = v4.z; kvc[4 * i + 3] = v4.w;
  }
#pragma unroll
  for (int i = 0; i < 16; i++) {
    const int row = rg * 16 + i;
    float a = 0.f;
#pragma unroll
    for (int e4 = 0; e4 < 16; e4++) {
      float4 qv = *(const float4*)&qs[row][e4 * 4];
      a = fmaf(qv.x, kvc[4 * e4 + 0], a);
      a = fmaf(qv.y, kvc[4 * e4 + 1], a);
      a = fmaf(qv.z, kvc[4 * e4 + 2], a);
      a = fmaf(qv.w, kvc[4 * e4 + 3], a);
    }
    const float val = a * zl[row];
    hout[(size_t)(b * N_SEQ + n0 + row) * C_ + h * E_ + f] = f2bf(val);
  }
}

// ---------------------------------------------------------------- launcher
extern "C" void kernel_launch(void* const* d_in, const int* in_sizes, int n_in,
                              void* d_out, int out_size, void* d_ws, size_t ws_size,
                              hipStream_t stream) {
  const float* x  = (const float*)d_in[0];
  const float* wq = (const float*)d_in[1];
  const float* wp = (const float*)d_in[2];
  const float* bp = (const float*)d_in[3];
  float* out = (float*)d_out;

  char* ws = (char*)d_ws;
  const size_t SZ_XBF  = (size_t)M_TOT * C_ * 2;      //  67108864
  const size_t SZ_QKV  = (size_t)M_TOT * QKVN * 2;    // 201326592
  const size_t SZ_WQ   = (size_t)QKVN * C_ * 2;       //   1572864
  const size_t SZ_WP   = (size_t)C_ * C_ * 2;         //    524288
  const size_t SZ_KVT  = (size_t)128 * 64 * 64 * 4;   //   2097152
  unsigned short* x_bf   = (unsigned short*)(ws);
  unsigned short* qkv_bf = (unsigned short*)(ws + SZ_XBF);
  unsigned short* wq_bf  = (unsigned short*)(ws + SZ_XBF + SZ_QKV);
  unsigned short* wp_bf  = (unsigned short*)(ws + SZ_XBF + SZ_QKV + SZ_WQ);
  float* KVT   = (float*)(ws + SZ_XBF + SZ_QKV + SZ_WQ + SZ_WP);
  float* ksumb = (float*)(ws + SZ_XBF + SZ_QKV + SZ_WQ + SZ_WP + SZ_KVT);
  unsigned short* hout = x_bf;  // reuse: x_bf dead after GEMM1

  (void)hipMemsetAsync(KVT, 0, SZ_KVT + 128 * 64 * 4, stream);

  cvt_bf16<<<16384, 256, 0, stream>>>(x, x_bf);
  cvt_bf16<<<384, 256, 0, stream>>>(wq, wq_bf);
  cvt_bf16<<<128, 256, 0, stream>>>(wp, wp_bf);

  gemm_bt<1><<<3072, 256, 0, stream>>>(x_bf, wq_bf, qkv_bf, nullptr, ksumb,
                                       M_TOT, QKVN, 6);
  kv_mfma<<<1024, 256, 0, stream>>>(qkv_bf, KVT);
  attn_out<<<8192, 256, 0, stream>>>(qkv_bf, KVT, ksumb, hout);
  gemm_bt<2><<<1024, 256, 0, stream>>>(hout, wp_bf, out, bp, nullptr,
                                       M_TOT, C_, 2);
}